// Round 1
// baseline (5194.896 us; speedup 1.0000x reference)
//
#include <hip/hip_runtime.h>

// SNN 2-layer forward: s2 = (( (x@W1.T >=1) @ W2.T) >= 1)
// B=4096, IN=3136, FEAT=6272, OUT=500. x and hidden spikes are binary.
// Output spikes are a hard threshold -> results must match the float64
// numpy reference bit-exactly. fp32 accumulation flips ~1-2 spikes per run
// (25.7M v1 values, pdf(1.0)~0.21, fp32 error ~1e-7) -> accumulate in fp64.

namespace {
constexpr int kB = 4096;
constexpr int kIn = 3136;    // 98 chunks of 32
constexpr int kFeat = 6272;  // 196 chunks of 32
constexpr int kOut = 500;
constexpr int kFeatWords = kFeat / 32;  // 196 u32 per batch row
}  // namespace

// ---------------------------------------------------------------------------
// FC1: v1 = x @ W1.T (fp64 acc), s1 = (v1 >= 1.0) packed as bits into s1bits.
// 64x64 output tile per block, 256 threads, 4x4 fp64 acc per thread, BK=32.
// Tiles staged into LDS already converted to f64 -> inner loop is
// ds_read_b128 + v_fma_f64 only.
// ---------------------------------------------------------------------------
__global__ __launch_bounds__(256) void snn_fc1(const float* __restrict__ x,
                                               const float* __restrict__ W1,
                                               unsigned int* __restrict__ s1bits) {
  __shared__ double Xd[32][66];  // [k'][b'], pad 66 (528B stride, 16B aligned)
  __shared__ double Wd[32][66];  // [k'][f']
  __shared__ unsigned int spikes[64][2];

  const int tid = threadIdx.x;
  const int tx = tid & 15;   // feature quad   (4 f each)
  const int ty = tid >> 4;   // batch quad     (4 b each)
  const int b0 = blockIdx.y * 64;
  const int f0 = blockIdx.x * 64;

  if (tid < 128) spikes[tid >> 1][tid & 1] = 0u;

  double acc[4][4];
#pragma unroll
  for (int j = 0; j < 4; ++j)
#pragma unroll
    for (int i = 0; i < 4; ++i) acc[j][i] = 0.0;

  // staging assignment: each thread loads 8 consecutive f32 of one row
  const int rl = tid >> 2;        // row in tile 0..63
  const int kq = (tid & 3) * 8;   // k offset within BK
  const float* xrow = x + (size_t)(b0 + rl) * kIn + kq;
  const float* wrow = W1 + (size_t)(f0 + rl) * kIn + kq;

  for (int kc = 0; kc < kIn; kc += 32) {
    const float4 xv0 = *(const float4*)(xrow + kc);
    const float4 xv1 = *(const float4*)(xrow + kc + 4);
    const float4 wv0 = *(const float4*)(wrow + kc);
    const float4 wv1 = *(const float4*)(wrow + kc + 4);
    __syncthreads();  // previous tile fully consumed before overwrite
    Xd[kq + 0][rl] = (double)xv0.x;
    Xd[kq + 1][rl] = (double)xv0.y;
    Xd[kq + 2][rl] = (double)xv0.z;
    Xd[kq + 3][rl] = (double)xv0.w;
    Xd[kq + 4][rl] = (double)xv1.x;
    Xd[kq + 5][rl] = (double)xv1.y;
    Xd[kq + 6][rl] = (double)xv1.z;
    Xd[kq + 7][rl] = (double)xv1.w;
    Wd[kq + 0][rl] = (double)wv0.x;
    Wd[kq + 1][rl] = (double)wv0.y;
    Wd[kq + 2][rl] = (double)wv0.z;
    Wd[kq + 3][rl] = (double)wv0.w;
    Wd[kq + 4][rl] = (double)wv1.x;
    Wd[kq + 5][rl] = (double)wv1.y;
    Wd[kq + 6][rl] = (double)wv1.z;
    Wd[kq + 7][rl] = (double)wv1.w;
    __syncthreads();
#pragma unroll
    for (int k = 0; k < 32; ++k) {
      const double2 xa = *(const double2*)&Xd[k][ty * 4];
      const double2 xb = *(const double2*)&Xd[k][ty * 4 + 2];
      const double2 wa = *(const double2*)&Wd[k][tx * 4];
      const double2 wb = *(const double2*)&Wd[k][tx * 4 + 2];
      const double xv[4] = {xa.x, xa.y, xb.x, xb.y};
      const double wv[4] = {wa.x, wa.y, wb.x, wb.y};
#pragma unroll
      for (int j = 0; j < 4; ++j)
#pragma unroll
        for (int i = 0; i < 4; ++i) acc[j][i] += xv[j] * wv[i];
    }
  }

  // threshold in f64, pack bits: bit i of word w (row r) = spike of f = f0+32w+i
  __syncthreads();
#pragma unroll
  for (int j = 0; j < 4; ++j) {
    unsigned int nib = 0u;
#pragma unroll
    for (int i = 0; i < 4; ++i) nib |= (acc[j][i] >= 1.0 ? 1u : 0u) << i;
    atomicOr(&spikes[ty * 4 + j][tx >> 3], nib << ((tx * 4) & 31));
  }
  __syncthreads();
  if (tid < 128) {
    const int r = tid >> 1;
    const int w = tid & 1;
    s1bits[(size_t)(b0 + r) * kFeatWords + (f0 >> 5) + w] = spikes[r][w];
  }
}

// ---------------------------------------------------------------------------
// FC2: v2 = s1 @ W2.T (fp64 acc), out = (v2 >= 1.0) as f32 0/1.
// s1 read from packed bits; 64x64 tile (o padded 500->512, masked stores).
// ---------------------------------------------------------------------------
__global__ __launch_bounds__(256) void snn_fc2(const unsigned int* __restrict__ s1bits,
                                               const float* __restrict__ W2,
                                               float* __restrict__ out) {
  __shared__ double Wd[32][66];
  __shared__ unsigned int Sb[64];

  const int tid = threadIdx.x;
  const int tx = tid & 15;  // output quad
  const int ty = tid >> 4;  // batch quad
  const int b0 = blockIdx.y * 64;
  const int o0 = blockIdx.x * 64;

  double acc[4][4];
#pragma unroll
  for (int j = 0; j < 4; ++j)
#pragma unroll
    for (int i = 0; i < 4; ++i) acc[j][i] = 0.0;

  const int rl = tid >> 2;
  const int kq = (tid & 3) * 8;
  int orow = o0 + rl;
  if (orow >= kOut) orow = kOut - 1;  // clamp; results masked at store
  const float* wrow = W2 + (size_t)orow * kFeat + kq;

  for (int kc = 0; kc < kFeat; kc += 32) {
    const float4 wv0 = *(const float4*)(wrow + kc);
    const float4 wv1 = *(const float4*)(wrow + kc + 4);
    unsigned int sword = 0u;
    if (tid < 64) sword = s1bits[(size_t)(b0 + tid) * kFeatWords + (kc >> 5)];
    __syncthreads();
    Wd[kq + 0][rl] = (double)wv0.x;
    Wd[kq + 1][rl] = (double)wv0.y;
    Wd[kq + 2][rl] = (double)wv0.z;
    Wd[kq + 3][rl] = (double)wv0.w;
    Wd[kq + 4][rl] = (double)wv1.x;
    Wd[kq + 5][rl] = (double)wv1.y;
    Wd[kq + 6][rl] = (double)wv1.z;
    Wd[kq + 7][rl] = (double)wv1.w;
    if (tid < 64) Sb[tid] = sword;
    __syncthreads();
    const unsigned int rw0 = Sb[ty * 4 + 0];
    const unsigned int rw1 = Sb[ty * 4 + 1];
    const unsigned int rw2 = Sb[ty * 4 + 2];
    const unsigned int rw3 = Sb[ty * 4 + 3];
#pragma unroll
    for (int k = 0; k < 32; ++k) {
      const double2 wa = *(const double2*)&Wd[k][tx * 4];
      const double2 wb = *(const double2*)&Wd[k][tx * 4 + 2];
      const double wv[4] = {wa.x, wa.y, wb.x, wb.y};
      const double sv[4] = {(double)((rw0 >> k) & 1u), (double)((rw1 >> k) & 1u),
                            (double)((rw2 >> k) & 1u), (double)((rw3 >> k) & 1u)};
#pragma unroll
      for (int j = 0; j < 4; ++j)
#pragma unroll
        for (int i = 0; i < 4; ++i) acc[j][i] += sv[j] * wv[i];
    }
  }

#pragma unroll
  for (int j = 0; j < 4; ++j) {
    const int b = b0 + ty * 4 + j;
#pragma unroll
    for (int i = 0; i < 4; ++i) {
      const int o = o0 + tx * 4 + i;
      if (o < kOut) out[(size_t)b * kOut + o] = (acc[j][i] >= 1.0) ? 1.0f : 0.0f;
    }
  }
}

extern "C" void kernel_launch(void* const* d_in, const int* in_sizes, int n_in,
                              void* d_out, int out_size, void* d_ws, size_t ws_size,
                              hipStream_t stream) {
  const float* x = (const float*)d_in[0];
  const float* W1 = (const float*)d_in[1];
  const float* W2 = (const float*)d_in[2];
  float* out = (float*)d_out;
  unsigned int* s1bits = (unsigned int*)d_ws;  // 4096*196 u32 = 3.2 MB

  snn_fc1<<<dim3(kFeat / 64, kB / 64), 256, 0, stream>>>(x, W1, s1bits);
  snn_fc2<<<dim3((kOut + 63) / 64, kB / 64), 256, 0, stream>>>(s1bits, W2, out);
}

// Round 2
// 1665.669 us; speedup vs baseline: 3.1188x; 3.1188x over previous
//
#include <hip/hip_runtime.h>

// SNN 2-layer forward: s2 = (( (x@W1.T >=1) @ W2.T) >= 1)
// B=4096, IN=3136, FEAT=6272, OUT=500; x and s1 are binary {0,1}.
// Output is a hard threshold -> must match the float64 numpy reference's
// DECISIONS. Strategy: exact i8-MFMA limb GEMM for FC1.
//   w = sum_{j=0..4} d_j * 2^{-7(j+1)},  d_j in [-64,64] (signed base-128
//   digits; split exact in f32; truncation < 2^-36 only for |w| < 2^-11).
//   v1 = sum_j (x . d_j) * 2^{-7(j+1)} with i32 MFMA accumulation (exact,
//   |acc| < 2^18) recombined in f64 (<=46 bits, exact). Residual vs f64
//   ref: rms ~5e-11 per dot -> ~2e-4 expected spike flips per run.
// FC2 (small, 120us) stays fp64-exact reading packed s1 bits.

namespace {
constexpr int kB = 4096;
constexpr int kIn = 3136;    // 49 chunks of 64
constexpr int kFeat = 6272;  // 98 chunks of 64
constexpr int kOut = 500;
constexpr int kFeatWords = kFeat / 32;                      // 196
constexpr size_t kPlane = (size_t)kFeat * kIn;              // 19,668,992
constexpr size_t kS1Bytes = (size_t)kB * kFeatWords * 4;    // 3,211,264
constexpr size_t kXqBytes = (size_t)kB * kIn;               // 12,845,056
}  // namespace

typedef int v4i __attribute__((ext_vector_type(4)));
typedef int v16i __attribute__((ext_vector_type(16)));

struct alignas(4) i8x4 { signed char x, y, z, w; };

__device__ __forceinline__ void gload_lds16(const void* g, void* l) {
  __builtin_amdgcn_global_load_lds((__attribute__((address_space(1))) void*)(g),
                                   (__attribute__((address_space(3))) void*)(l),
                                   16, 0, 0);
}

// exact 5-digit signed base-128 split of f32 (|w| << 0.5)
__device__ __forceinline__ void split5(float w, signed char* d) {
  float c = rintf(w * 128.f);
  d[0] = (signed char)(int)c;
  float r = fmaf(c, -7.8125e-03f, w);            // 2^-7 (exact)
  c = rintf(r * 16384.f);
  d[1] = (signed char)(int)c;
  r = fmaf(c, -6.103515625e-05f, r);             // 2^-14 (exact)
  c = rintf(r * 2097152.f);
  d[2] = (signed char)(int)c;
  r = fmaf(c, -4.76837158203125e-07f, r);        // 2^-21 (exact)
  c = rintf(r * 268435456.f);
  d[3] = (signed char)(int)c;
  r = fmaf(c, -3.725290298461914e-09f, r);       // 2^-28 (exact)
  c = rintf(r * 3.4359738368e+10f);              // 2^35
  d[4] = (signed char)(int)c;
}

// ---------------------------------------------------------------------------
// W1 [6272][3136] f32 -> 5 i8 planes [6272][3136]
// ---------------------------------------------------------------------------
__global__ __launch_bounds__(256) void conv_w1(const float* __restrict__ W,
                                               signed char* __restrict__ L) {
  const size_t i = (size_t)blockIdx.x * 256 + threadIdx.x;  // < 4,917,248
  const float4 w = ((const float4*)W)[i];
  signed char d0[5], d1[5], d2[5], d3[5];
  split5(w.x, d0);
  split5(w.y, d1);
  split5(w.z, d2);
  split5(w.w, d3);
#pragma unroll
  for (int j = 0; j < 5; ++j) {
    i8x4 o{d0[j], d1[j], d2[j], d3[j]};
    *(i8x4*)(L + j * kPlane + i * 4) = o;
  }
}

// x f32 (exactly 0.0/1.0) -> i8
__global__ __launch_bounds__(256) void conv_x(const float* __restrict__ X,
                                              signed char* __restrict__ q) {
  const size_t i = (size_t)blockIdx.x * 256 + threadIdx.x;  // < 3,211,264
  const float4 v = ((const float4*)X)[i];
  i8x4 o{(signed char)(v.x != 0.f), (signed char)(v.y != 0.f),
         (signed char)(v.z != 0.f), (signed char)(v.w != 0.f)};
  *(i8x4*)(q + i * 4) = o;
}

// ---------------------------------------------------------------------------
// FC1 i8 limb GEMM. Block: 512 thr = 8 waves, tile M=256 (batch) x N=64
// (feat), BK=64. Wave tile 64x32 = 2 Msub x 1 Nsub x 5 limbs = 10 v16i acc.
// LDS K-major 16B-grouped: A[g][row][16], B[j][g][n][16] -> staging matches
// global_load_lds (uniform base + lane*16) AND frag ds_read_b128 is the
// identity pattern (lane&31 -> consecutive 16B) => conflict-free.
// MFMA layout assumed: A m=lane&31, k=(lane>>5)*16+i; B n=lane&31 same k;
// C/D col(n)=lane&31, row(m)=(t&3)+8*(t>>2)+4*(lane>>5).
// ---------------------------------------------------------------------------
__global__ __launch_bounds__(512) void snn_fc1_i8(const signed char* __restrict__ xq,
                                                  const signed char* __restrict__ w1l,
                                                  unsigned int* __restrict__ s1bits) {
  __shared__ __align__(16) signed char lds[36864];  // A 16K, B 20K
  const int tid = threadIdx.x;
  const int lane = tid & 63;
  const int ln31 = lane & 31;
  const int half = lane >> 5;
  const int wv = tid >> 6;     // 0..7
  const int waveM = wv >> 1;   // 0..3
  const int waveN = wv & 1;    // 0..1
  const int bM = blockIdx.y * 256;
  const int bN = blockIdx.x * 64;

  // staging slots for this wave: idx<16 -> A (g=idx&3, rowgroup=idx>>2);
  // else B (e=idx-16: limb=e>>2, g=e&3). lof is wave-uniform.
  const signed char* gb[5];
  unsigned lof[5];
#pragma unroll
  for (int s = 0; s < 5; ++s) {
    const int idx = wv + s * 8;
    if (idx < 36) {
      if (idx < 16) {
        const int g = idx & 3, rg = idx >> 2;
        gb[s] = xq + (size_t)(bM + rg * 64 + lane) * kIn + g * 16;
        lof[s] = g * 4096u + rg * 1024u;
      } else {
        const int e = idx - 16;
        const int j = e >> 2, g = e & 3;
        gb[s] = w1l + (size_t)j * kPlane + (size_t)(bN + lane) * kIn + g * 16;
        lof[s] = 16384u + j * 4096u + g * 1024u;
      }
    }
  }

  // fixed LDS frag addresses (tile reused every iter)
  unsigned aoff[2][2], boff[2][5];
#pragma unroll
  for (int kk = 0; kk < 2; ++kk) {
    const int g = kk * 2 + half;
#pragma unroll
    for (int m = 0; m < 2; ++m)
      aoff[kk][m] = g * 4096u + (waveM * 64 + m * 32 + ln31) * 16u;
#pragma unroll
    for (int j = 0; j < 5; ++j)
      boff[kk][j] = 16384u + j * 4096u + g * 1024u + (waveN * 32 + ln31) * 16u;
  }

  v16i acc[2][5] = {};

  for (int kt = 0; kt < 49; ++kt) {
    const int kc = kt * 64;
    __syncthreads();  // previous tile consumed
#pragma unroll
    for (int s = 0; s < 5; ++s)
      if (wv + s * 8 < 36) gload_lds16(gb[s] + kc, lds + lof[s]);
    __syncthreads();  // compiler drains vmcnt before barrier
#pragma unroll
    for (int kk = 0; kk < 2; ++kk) {
      const v4i a0 = *(const v4i*)(lds + aoff[kk][0]);
      const v4i a1 = *(const v4i*)(lds + aoff[kk][1]);
#pragma unroll
      for (int j = 0; j < 5; ++j) {
        const v4i b = *(const v4i*)(lds + boff[kk][j]);
        acc[0][j] = __builtin_amdgcn_mfma_i32_32x32x32_i8(a0, b, acc[0][j], 0, 0, 0);
        acc[1][j] = __builtin_amdgcn_mfma_i32_32x32x32_i8(a1, b, acc[1][j], 0, 0, 0);
      }
    }
  }

  // recombine limbs in f64 (exact), threshold, pack bits via ballot
  const double s7 = 0.0078125;  // 2^-7
  const int word = (bN >> 5) + waveN;
#pragma unroll
  for (int m = 0; m < 2; ++m) {
#pragma unroll
    for (int t = 0; t < 16; ++t) {
      double v = (double)acc[m][4][t];
      v = v * s7 + (double)acc[m][3][t];
      v = v * s7 + (double)acc[m][2][t];
      v = v * s7 + (double)acc[m][1][t];
      v = v * s7 + (double)acc[m][0][t];
      v = v * s7;
      const unsigned long long bal = __ballot(v >= 1.0);
      const int mrow = bM + waveM * 64 + m * 32 + (t & 3) + ((t >> 2) * 8);
      if (lane == 0) s1bits[(size_t)mrow * kFeatWords + word] = (unsigned)bal;
      if (lane == 32) s1bits[(size_t)(mrow + 4) * kFeatWords + word] = (unsigned)(bal >> 32);
    }
  }
}

// ---------------------------------------------------------------------------
// FC1 fp64 fallback (validated round 1) — used only if ws_size too small.
// ---------------------------------------------------------------------------
__global__ __launch_bounds__(256) void snn_fc1(const float* __restrict__ x,
                                               const float* __restrict__ W1,
                                               unsigned int* __restrict__ s1bits) {
  __shared__ double Xd[32][66];
  __shared__ double Wd[32][66];
  __shared__ unsigned int spikes[64][2];

  const int tid = threadIdx.x;
  const int tx = tid & 15;
  const int ty = tid >> 4;
  const int b0 = blockIdx.y * 64;
  const int f0 = blockIdx.x * 64;

  if (tid < 128) spikes[tid >> 1][tid & 1] = 0u;

  double acc[4][4];
#pragma unroll
  for (int j = 0; j < 4; ++j)
#pragma unroll
    for (int i = 0; i < 4; ++i) acc[j][i] = 0.0;

  const int rl = tid >> 2;
  const int kq = (tid & 3) * 8;
  const float* xrow = x + (size_t)(b0 + rl) * kIn + kq;
  const float* wrow = W1 + (size_t)(f0 + rl) * kIn + kq;

  for (int kc = 0; kc < kIn; kc += 32) {
    const float4 xv0 = *(const float4*)(xrow + kc);
    const float4 xv1 = *(const float4*)(xrow + kc + 4);
    const float4 wv0 = *(const float4*)(wrow + kc);
    const float4 wv1 = *(const float4*)(wrow + kc + 4);
    __syncthreads();
    Xd[kq + 0][rl] = (double)xv0.x; Xd[kq + 1][rl] = (double)xv0.y;
    Xd[kq + 2][rl] = (double)xv0.z; Xd[kq + 3][rl] = (double)xv0.w;
    Xd[kq + 4][rl] = (double)xv1.x; Xd[kq + 5][rl] = (double)xv1.y;
    Xd[kq + 6][rl] = (double)xv1.z; Xd[kq + 7][rl] = (double)xv1.w;
    Wd[kq + 0][rl] = (double)wv0.x; Wd[kq + 1][rl] = (double)wv0.y;
    Wd[kq + 2][rl] = (double)wv0.z; Wd[kq + 3][rl] = (double)wv0.w;
    Wd[kq + 4][rl] = (double)wv1.x; Wd[kq + 5][rl] = (double)wv1.y;
    Wd[kq + 6][rl] = (double)wv1.z; Wd[kq + 7][rl] = (double)wv1.w;
    __syncthreads();
#pragma unroll
    for (int k = 0; k < 32; ++k) {
      const double2 xa = *(const double2*)&Xd[k][ty * 4];
      const double2 xb = *(const double2*)&Xd[k][ty * 4 + 2];
      const double2 wa = *(const double2*)&Wd[k][tx * 4];
      const double2 wb = *(const double2*)&Wd[k][tx * 4 + 2];
      const double xv[4] = {xa.x, xa.y, xb.x, xb.y};
      const double wv[4] = {wa.x, wa.y, wb.x, wb.y};
#pragma unroll
      for (int j = 0; j < 4; ++j)
#pragma unroll
        for (int i = 0; i < 4; ++i) acc[j][i] += xv[j] * wv[i];
    }
  }

  __syncthreads();
#pragma unroll
  for (int j = 0; j < 4; ++j) {
    unsigned int nib = 0u;
#pragma unroll
    for (int i = 0; i < 4; ++i) nib |= (acc[j][i] >= 1.0 ? 1u : 0u) << i;
    atomicOr(&spikes[ty * 4 + j][tx >> 3], nib << ((tx * 4) & 31));
  }
  __syncthreads();
  if (tid < 128) {
    const int r = tid >> 1;
    const int w = tid & 1;
    s1bits[(size_t)(b0 + r) * kFeatWords + (f0 >> 5) + w] = spikes[r][w];
  }
}

// ---------------------------------------------------------------------------
// FC2 fp64 (validated round 1): v2 = s1 @ W2.T, out = (v2 >= 1) as f32.
// ---------------------------------------------------------------------------
__global__ __launch_bounds__(256) void snn_fc2(const unsigned int* __restrict__ s1bits,
                                               const float* __restrict__ W2,
                                               float* __restrict__ out) {
  __shared__ double Wd[32][66];
  __shared__ unsigned int Sb[64];

  const int tid = threadIdx.x;
  const int tx = tid & 15;
  const int ty = tid >> 4;
  const int b0 = blockIdx.y * 64;
  const int o0 = blockIdx.x * 64;

  double acc[4][4];
#pragma unroll
  for (int j = 0; j < 4; ++j)
#pragma unroll
    for (int i = 0; i < 4; ++i) acc[j][i] = 0.0;

  const int rl = tid >> 2;
  const int kq = (tid & 3) * 8;
  int orow = o0 + rl;
  if (orow >= kOut) orow = kOut - 1;
  const float* wrow = W2 + (size_t)orow * kFeat + kq;

  for (int kc = 0; kc < kFeat; kc += 32) {
    const float4 wv0 = *(const float4*)(wrow + kc);
    const float4 wv1 = *(const float4*)(wrow + kc + 4);
    unsigned int sword = 0u;
    if (tid < 64) sword = s1bits[(size_t)(b0 + tid) * kFeatWords + (kc >> 5)];
    __syncthreads();
    Wd[kq + 0][rl] = (double)wv0.x; Wd[kq + 1][rl] = (double)wv0.y;
    Wd[kq + 2][rl] = (double)wv0.z; Wd[kq + 3][rl] = (double)wv0.w;
    Wd[kq + 4][rl] = (double)wv1.x; Wd[kq + 5][rl] = (double)wv1.y;
    Wd[kq + 6][rl] = (double)wv1.z; Wd[kq + 7][rl] = (double)wv1.w;
    if (tid < 64) Sb[tid] = sword;
    __syncthreads();
    const unsigned int rw0 = Sb[ty * 4 + 0];
    const unsigned int rw1 = Sb[ty * 4 + 1];
    const unsigned int rw2 = Sb[ty * 4 + 2];
    const unsigned int rw3 = Sb[ty * 4 + 3];
#pragma unroll
    for (int k = 0; k < 32; ++k) {
      const double2 wa = *(const double2*)&Wd[k][tx * 4];
      const double2 wb = *(const double2*)&Wd[k][tx * 4 + 2];
      const double wv[4] = {wa.x, wa.y, wb.x, wb.y};
      const double sv[4] = {(double)((rw0 >> k) & 1u), (double)((rw1 >> k) & 1u),
                            (double)((rw2 >> k) & 1u), (double)((rw3 >> k) & 1u)};
#pragma unroll
      for (int j = 0; j < 4; ++j)
#pragma unroll
        for (int i = 0; i < 4; ++i) acc[j][i] += sv[j] * wv[i];
    }
  }

#pragma unroll
  for (int j = 0; j < 4; ++j) {
    const int b = b0 + ty * 4 + j;
#pragma unroll
    for (int i = 0; i < 4; ++i) {
      const int o = o0 + tx * 4 + i;
      if (o < kOut) out[(size_t)b * kOut + o] = (acc[j][i] >= 1.0) ? 1.0f : 0.0f;
    }
  }
}

extern "C" void kernel_launch(void* const* d_in, const int* in_sizes, int n_in,
                              void* d_out, int out_size, void* d_ws, size_t ws_size,
                              hipStream_t stream) {
  const float* x = (const float*)d_in[0];
  const float* W1 = (const float*)d_in[1];
  const float* W2 = (const float*)d_in[2];
  float* out = (float*)d_out;

  const size_t need = 5 * kPlane + kS1Bytes + kXqBytes;  // ~114.4 MB
  if (ws_size >= need) {
    signed char* w1l = (signed char*)d_ws;
    unsigned int* s1b = (unsigned int*)((char*)d_ws + 5 * kPlane);
    signed char* xq = (signed char*)((char*)d_ws + 5 * kPlane + kS1Bytes);
    conv_w1<<<19208, 256, 0, stream>>>(W1, w1l);   // 4,917,248 f32x4 groups
    conv_x<<<12544, 256, 0, stream>>>(x, xq);      // 3,211,264 f32x4 groups
    snn_fc1_i8<<<dim3(98, 16), 512, 0, stream>>>(xq, w1l, s1b);
    snn_fc2<<<dim3(8, 64), 256, 0, stream>>>(s1b, W2, out);
  } else {
    unsigned int* s1b = (unsigned int*)d_ws;
    snn_fc1<<<dim3(98, 64), 256, 0, stream>>>(x, W1, s1b);
    snn_fc2<<<dim3(8, 64), 256, 0, stream>>>(s1b, W2, out);
  }
}

// Round 4
// 764.139 us; speedup vs baseline: 6.7984x; 2.1798x over previous
//
#include <hip/hip_runtime.h>

// SNN 2-layer forward: s2 = (( (x@W1.T >=1) @ W2.T) >= 1)
// B=4096, IN=3136, FEAT=6272, OUT=500; x and s1 are binary {0,1}.
// Strategy: 3-limb exact i8 MFMA GEMM + worst-case-safe sparse fp64
// correction.
//   w = d0*2^-7 + d1*2^-14 + d2*2^-21 + r,  |r| <= 2^-22, d_j in [-64,64].
//   v_hat = Horner(S0,S1,S2) exact in f64 (i32 MFMA sums are exact).
//   |v - v_hat| <= K*2^-22  -> flag |v_hat-1| <= tau, recompute flagged
//   dots in fp64 (expected ~8K for FC1, ~15 for FC2) -> provably exact.
// A-operands (binary) are carried as packed bits and expanded to i8 in LDS
// via (nib*0x204081)&0x01010101 -> cuts A-side HBM 8x and LDS pressure.
//
// ROUND-3 BUG FIX: zero 32 bytes of ctrs, not 16. ctrs+4 (FC2 counter,
// byte offset 16) was left at the 0xAA poison -> fc2_correct read 64K
// poisoned list entries -> OOB s1bits reads -> device abort.

namespace {
constexpr int kB = 4096;
constexpr int kIn = 3136;        // 49 chunks of 64
constexpr int kInWords = 98;     // u32 words per x row
constexpr int kFeat = 6272;      // 98 chunks of 64
constexpr int kFeatWords = 196;  // u32 words per s1 row
constexpr int kOut = 500;
constexpr int kOutPad = 512;
constexpr size_t kPlane1 = (size_t)kFeat * kIn;     // 19,668,992
constexpr size_t kPlane2 = (size_t)kOutPad * kFeat; // 3,211,264
constexpr size_t kW1lBytes = 3 * kPlane1;           // 59,006,976
constexpr size_t kW2lBytes = 3 * kPlane2;           //  9,633,792
constexpr size_t kS1Bytes = (size_t)kB * kFeatWords * 4;  // 3,211,264
constexpr size_t kXbBytes = (size_t)kB * kInWords * 4;    // 1,605,632
constexpr unsigned kCap1 = 2u << 20;                // 2M entries
constexpr unsigned kCap2 = 1u << 16;                // 64K entries
constexpr size_t kList1Bytes = (size_t)kCap1 * 4;   // 8,388,608
constexpr size_t kList2Bytes = (size_t)kCap2 * 4;   // 262,144
__device__ constexpr double kTau1 = 7.4769e-4;      // > 3136*2^-22
__device__ constexpr double kTau2 = 1.4955e-3;      // > 6272*2^-22
}  // namespace

typedef int v4i __attribute__((ext_vector_type(4)));
typedef int v16i __attribute__((ext_vector_type(16)));

struct alignas(4) i8x4 { signed char x, y, z, w; };

__device__ __forceinline__ void gload_lds16(const void* g, void* l) {
  __builtin_amdgcn_global_load_lds((__attribute__((address_space(1))) void*)(g),
                                   (__attribute__((address_space(3))) void*)(l),
                                   16, 0, 0);
}

// exact 3-digit signed base-128 split; residual |w - sum| <= 2^-22
__device__ __forceinline__ void split3(float w, signed char* d) {
  float c = rintf(w * 128.f);
  d[0] = (signed char)(int)c;
  float r = fmaf(c, -7.8125e-03f, w);       // - c*2^-7  (exact)
  c = rintf(r * 16384.f);
  d[1] = (signed char)(int)c;
  r = fmaf(c, -6.103515625e-05f, r);        // - c*2^-14 (exact)
  c = rintf(r * 2097152.f);
  d[2] = (signed char)(int)c;
}

// ---------------------------------------------------------------------------
// W1 [6272][3136] f32 -> 3 i8 planes
// ---------------------------------------------------------------------------
__global__ __launch_bounds__(256) void conv_w1_3(const float* __restrict__ W,
                                                 signed char* __restrict__ L) {
  const size_t i = (size_t)blockIdx.x * 256 + threadIdx.x;  // < 4,917,248
  const float4 w = ((const float4*)W)[i];
  signed char a[3], b[3], c[3], d[3];
  split3(w.x, a);
  split3(w.y, b);
  split3(w.z, c);
  split3(w.w, d);
#pragma unroll
  for (int j = 0; j < 3; ++j) {
    i8x4 o{a[j], b[j], c[j], d[j]};
    *(i8x4*)(L + j * kPlane1 + i * 4) = o;
  }
}

// W2 [500][6272] f32 -> 3 i8 planes padded to [512][6272] (pad rows = 0)
__global__ __launch_bounds__(256) void conv_w2_3(const float* __restrict__ W,
                                                 signed char* __restrict__ L) {
  const size_t i = (size_t)blockIdx.x * 256 + threadIdx.x;  // < 802,816
  const int row = (int)(i / 1568);   // 6272/4
  const int c4 = (int)(i % 1568);
  float4 w = {0.f, 0.f, 0.f, 0.f};
  if (row < kOut) w = *(const float4*)(W + (size_t)row * kFeat + c4 * 4);
  signed char a[3], b[3], c[3], d[3];
  split3(w.x, a);
  split3(w.y, b);
  split3(w.z, c);
  split3(w.w, d);
#pragma unroll
  for (int j = 0; j < 3; ++j) {
    i8x4 o{a[j], b[j], c[j], d[j]};
    *(i8x4*)(L + j * kPlane2 + i * 4) = o;
  }
}

// x f32 (0.0/1.0) -> packed bits [4096][98 u32]; one wave packs 64 bits
__global__ __launch_bounds__(256) void pack_x(const float* __restrict__ X,
                                              unsigned* __restrict__ xb) {
  const int wid = (blockIdx.x * 256 + threadIdx.x) >> 6;  // < 200,704
  const int lane = threadIdx.x & 63;
  const int b = wid / 49;
  const int g = wid % 49;
  const float v = X[(size_t)b * kIn + g * 64 + lane];
  const unsigned long long bal = __ballot(v != 0.f);
  if (lane == 0) xb[b * kInWords + g * 2] = (unsigned)bal;
  if (lane == 32) xb[b * kInWords + g * 2 + 1] = (unsigned)(bal >> 32);
}

// ---------------------------------------------------------------------------
// FC1: 3-limb i8 GEMM. Block 512 thr = 8 waves, tile M=256 x N=64, BK=64.
// Wave tile 64x32: acc[2 m][3 j] (96 AGPR). A expanded from bits in LDS.
// LDS: A[g 0..3][row 0..255][16B] = 16K, B[j][g][n][16B] = 12K at 16384.
// ---------------------------------------------------------------------------
__global__ __launch_bounds__(512) void snn_fc1_i8l3(
    const unsigned* __restrict__ xbits, const signed char* __restrict__ w1l,
    unsigned* __restrict__ s1bits, unsigned* __restrict__ cnt,
    unsigned* __restrict__ list) {
  __shared__ __align__(16) signed char lds[28672];
  const int tid = threadIdx.x;
  const int lane = tid & 63;
  const int ln31 = lane & 31;
  const int half = lane >> 5;
  const int wv = tid >> 6;
  const int waveM = wv >> 1;  // 0..3
  const int waveN = wv & 1;   // 0..1
  const int bM = blockIdx.y * 256;
  const int bN = blockIdx.x * 64;

  // B staging: 12 slots (j 0..2, g 0..3); wave wv does slot wv and wv+8(<12)
  const signed char* gb[2];
  unsigned lof[2];
  const bool has1 = (wv < 4);
  {
    const int e0 = wv, e1 = wv + 8;
    gb[0] = w1l + (size_t)(e0 >> 2) * kPlane1 + (size_t)(bN + lane) * kIn + (e0 & 3) * 16;
    lof[0] = 16384u + (e0 >> 2) * 4096u + (e0 & 3) * 1024u;
    gb[1] = w1l + (size_t)(e1 >> 2) * kPlane1 + (size_t)(bN + lane) * kIn + (e1 & 3) * 16;
    lof[1] = 16384u + (e1 >> 2) * 4096u + (e1 & 3) * 1024u;
  }

  // A-expand assignment: thread -> (row, k-half)
  const int xrow = tid >> 1;        // 0..255
  const int xh = tid & 1;           // which 32-k half
  const unsigned* xwp = xbits + (size_t)(bM + xrow) * kInWords + xh;
  signed char* const awp0 = lds + (xh * 2) * 4096 + xrow * 16;
  signed char* const awp1 = lds + (xh * 2 + 1) * 4096 + xrow * 16;

  unsigned aoff[2][2], boff[2][3];
#pragma unroll
  for (int kk = 0; kk < 2; ++kk) {
    const int g = kk * 2 + half;
#pragma unroll
    for (int m = 0; m < 2; ++m)
      aoff[kk][m] = g * 4096u + (waveM * 64 + m * 32 + ln31) * 16u;
#pragma unroll
    for (int j = 0; j < 3; ++j)
      boff[kk][j] = 16384u + j * 4096u + g * 1024u + (waveN * 32 + ln31) * 16u;
  }

  v16i acc[2][3] = {};

  for (int kt = 0; kt < 49; ++kt) {
    const unsigned word = xwp[kt * 2];
    __syncthreads();  // previous tile consumed
    gload_lds16(gb[0] + kt * 64, lds + lof[0]);
    if (has1) gload_lds16(gb[1] + kt * 64, lds + lof[1]);
    unsigned u[8];
#pragma unroll
    for (int d = 0; d < 8; ++d)
      u[d] = (((word >> (4 * d)) & 0xFu) * 0x204081u) & 0x01010101u;
    *(v4i*)awp0 = (v4i){(int)u[0], (int)u[1], (int)u[2], (int)u[3]};
    *(v4i*)awp1 = (v4i){(int)u[4], (int)u[5], (int)u[6], (int)u[7]};
    __syncthreads();
#pragma unroll
    for (int kk = 0; kk < 2; ++kk) {
      const v4i a0 = *(const v4i*)(lds + aoff[kk][0]);
      const v4i a1 = *(const v4i*)(lds + aoff[kk][1]);
#pragma unroll
      for (int j = 0; j < 3; ++j) {
        const v4i b = *(const v4i*)(lds + boff[kk][j]);
        acc[0][j] = __builtin_amdgcn_mfma_i32_32x32x32_i8(a0, b, acc[0][j], 0, 0, 0);
        acc[1][j] = __builtin_amdgcn_mfma_i32_32x32x32_i8(a1, b, acc[1][j], 0, 0, 0);
      }
    }
  }

  const double s7 = 0.0078125;  // 2^-7
  const int word = (bN >> 5) + waveN;
  const int fcol = bN + waveN * 32 + ln31;
#pragma unroll
  for (int m = 0; m < 2; ++m) {
#pragma unroll
    for (int t = 0; t < 16; ++t) {
      double v = (double)acc[m][2][t];
      v = v * s7 + (double)acc[m][1][t];
      v = v * s7 + (double)acc[m][0][t];
      v = v * s7;
      const bool spike = (v >= 1.0);
      const unsigned long long bal = __ballot(spike);
      const int mrow = bM + waveM * 64 + m * 32 + (t & 3) + ((t >> 2) * 8);
      if (lane == 0) s1bits[(size_t)mrow * kFeatWords + word] = (unsigned)bal;
      if (lane == 32) s1bits[(size_t)(mrow + 4) * kFeatWords + word] = (unsigned)(bal >> 32);
      if (fabs(v - 1.0) <= kTau1) {  // possibly-wrong decision -> flag
        const unsigned idx = atomicAdd(cnt, 1u);
        if (idx < kCap1) list[idx] = ((unsigned)(mrow + 4 * half) << 13) | (unsigned)fcol;
      }
    }
  }
}

// exact fp64 recompute of flagged FC1 dots; fixes s1 bits
__global__ __launch_bounds__(256) void fc1_correct(const float* __restrict__ x,
                                                   const float* __restrict__ W1,
                                                   const unsigned* __restrict__ cnt,
                                                   const unsigned* __restrict__ list,
                                                   unsigned* __restrict__ s1bits) {
  const unsigned n = min(cnt[0], kCap1);
  const int lane = threadIdx.x & 63;
  const int wid = (blockIdx.x * 256 + threadIdx.x) >> 6;
  const int nw = (gridDim.x * 256) >> 6;
  for (unsigned i = wid; i < n; i += nw) {
    const unsigned u = list[i];
    const int b = (int)(u >> 13);
    const int f = (int)(u & 8191u);
    double s = 0.0;
    for (int k = lane; k < kIn; k += 64)
      s = fma((double)x[(size_t)b * kIn + k], (double)W1[(size_t)f * kIn + k], s);
#pragma unroll
    for (int off = 32; off > 0; off >>= 1) s += __shfl_down(s, off);
    if (lane == 0) {
      const unsigned mask = 1u << (f & 31);
      unsigned* w = s1bits + (size_t)b * kFeatWords + (f >> 5);
      if (s >= 1.0) atomicOr(w, mask); else atomicAnd(w, ~mask);
    }
  }
}

// ---------------------------------------------------------------------------
// FC2: 3-limb i8 GEMM. Block 512 thr, tile M=128 x N=64, BK=64, grid (8,32).
// Wave tile 32x32: acc[3 j]. A (s1) expanded from bits in LDS.
// LDS: A[g][row 0..127][16B] = 8K, B at 8192 = 12K.
// ---------------------------------------------------------------------------
__global__ __launch_bounds__(512) void snn_fc2_i8l3(
    const unsigned* __restrict__ s1bits, const signed char* __restrict__ w2l,
    float* __restrict__ out, unsigned* __restrict__ cnt,
    unsigned* __restrict__ list) {
  __shared__ __align__(16) signed char lds[20480];
  const int tid = threadIdx.x;
  const int lane = tid & 63;
  const int ln31 = lane & 31;
  const int half = lane >> 5;
  const int wv = tid >> 6;
  const int waveM = wv >> 1;  // 0..3
  const int waveN = wv & 1;   // 0..1
  const int bM = blockIdx.y * 128;
  const int bN = blockIdx.x * 64;

  const signed char* gb[2];
  unsigned lof[2];
  const bool has1 = (wv < 4);
  {
    const int e0 = wv, e1 = wv + 8;
    gb[0] = w2l + (size_t)(e0 >> 2) * kPlane2 + (size_t)(bN + lane) * kFeat + (e0 & 3) * 16;
    lof[0] = 8192u + (e0 >> 2) * 4096u + (e0 & 3) * 1024u;
    gb[1] = w2l + (size_t)(e1 >> 2) * kPlane2 + (size_t)(bN + lane) * kFeat + (e1 & 3) * 16;
    lof[1] = 8192u + (e1 >> 2) * 4096u + (e1 & 3) * 1024u;
  }

  const int xrow = tid >> 2;       // 0..127
  const int xg = tid & 3;          // 16-k group
  const unsigned* swp = s1bits + (size_t)(bM + xrow) * kFeatWords + (xg >> 1);
  const int xsh = (xg & 1) * 16;
  signed char* const awp = lds + xg * 2048 + xrow * 16;

  unsigned aoff[2], boff[2][3];
#pragma unroll
  for (int kk = 0; kk < 2; ++kk) {
    const int g = kk * 2 + half;
    aoff[kk] = g * 2048u + (waveM * 32 + ln31) * 16u;
#pragma unroll
    for (int j = 0; j < 3; ++j)
      boff[kk][j] = 8192u + j * 4096u + g * 1024u + (waveN * 32 + ln31) * 16u;
  }

  v16i acc[3] = {};

  for (int kt = 0; kt < 98; ++kt) {
    const unsigned bits16 = (swp[kt * 2] >> xsh) & 0xFFFFu;
    __syncthreads();
    gload_lds16(gb[0] + kt * 64, lds + lof[0]);
    if (has1) gload_lds16(gb[1] + kt * 64, lds + lof[1]);
    unsigned u[4];
#pragma unroll
    for (int d = 0; d < 4; ++d)
      u[d] = (((bits16 >> (4 * d)) & 0xFu) * 0x204081u) & 0x01010101u;
    *(v4i*)awp = (v4i){(int)u[0], (int)u[1], (int)u[2], (int)u[3]};
    __syncthreads();
#pragma unroll
    for (int kk = 0; kk < 2; ++kk) {
      const v4i a = *(const v4i*)(lds + aoff[kk]);
#pragma unroll
      for (int j = 0; j < 3; ++j) {
        const v4i b = *(const v4i*)(lds + boff[kk][j]);
        acc[j] = __builtin_amdgcn_mfma_i32_32x32x32_i8(a, b, acc[j], 0, 0, 0);
      }
    }
  }

  const double s7 = 0.0078125;
  const int o = bN + waveN * 32 + ln31;
#pragma unroll
  for (int t = 0; t < 16; ++t) {
    double v = (double)acc[2][t];
    v = v * s7 + (double)acc[1][t];
    v = v * s7 + (double)acc[0][t];
    v = v * s7;
    const int b = bM + waveM * 32 + (t & 3) + 8 * (t >> 2) + 4 * half;
    if (o < kOut) {
      out[(size_t)b * kOut + o] = (v >= 1.0) ? 1.0f : 0.0f;
      if (fabs(v - 1.0) <= kTau2) {
        const unsigned idx = atomicAdd(cnt, 1u);
        if (idx < kCap2) list[idx] = ((unsigned)b << 13) | (unsigned)o;
      }
    }
  }
}

// exact fp64 recompute of flagged FC2 dots; fixes out
__global__ __launch_bounds__(256) void fc2_correct(const unsigned* __restrict__ s1bits,
                                                   const float* __restrict__ W2,
                                                   const unsigned* __restrict__ cnt,
                                                   const unsigned* __restrict__ list,
                                                   float* __restrict__ out) {
  const unsigned n = min(cnt[0], kCap2);
  const int lane = threadIdx.x & 63;
  const int wid = (blockIdx.x * 256 + threadIdx.x) >> 6;
  const int nw = (gridDim.x * 256) >> 6;
  for (unsigned i = wid; i < n; i += nw) {
    const unsigned u = list[i];
    const int b = (int)(u >> 13);
    const int o = (int)(u & 8191u);
    double s = 0.0;
    for (int k = lane; k < kFeat; k += 64) {
      const unsigned w = s1bits[(size_t)b * kFeatWords + (k >> 5)];
      if ((w >> (k & 31)) & 1u) s += (double)W2[(size_t)o * kFeat + k];
    }
#pragma unroll
    for (int off = 32; off > 0; off >>= 1) s += __shfl_down(s, off);
    if (lane == 0) out[(size_t)b * kOut + o] = (s >= 1.0) ? 1.0f : 0.0f;
  }
}

// ---------------------------------------------------------------------------
// fp64 fallback path (validated round 1) — only if ws too small.
// ---------------------------------------------------------------------------
__global__ __launch_bounds__(256) void snn_fc1(const float* __restrict__ x,
                                               const float* __restrict__ W1,
                                               unsigned int* __restrict__ s1bits) {
  __shared__ double Xd[32][66];
  __shared__ double Wd[32][66];
  __shared__ unsigned int spikes[64][2];
  const int tid = threadIdx.x;
  const int tx = tid & 15;
  const int ty = tid >> 4;
  const int b0 = blockIdx.y * 64;
  const int f0 = blockIdx.x * 64;
  if (tid < 128) spikes[tid >> 1][tid & 1] = 0u;
  double acc[4][4];
#pragma unroll
  for (int j = 0; j < 4; ++j)
#pragma unroll
    for (int i = 0; i < 4; ++i) acc[j][i] = 0.0;
  const int rl = tid >> 2;
  const int kq = (tid & 3) * 8;
  const float* xrow = x + (size_t)(b0 + rl) * kIn + kq;
  const float* wrow = W1 + (size_t)(f0 + rl) * kIn + kq;
  for (int kc = 0; kc < kIn; kc += 32) {
    const float4 xv0 = *(const float4*)(xrow + kc);
    const float4 xv1 = *(const float4*)(xrow + kc + 4);
    const float4 wv0 = *(const float4*)(wrow + kc);
    const float4 wv1 = *(const float4*)(wrow + kc + 4);
    __syncthreads();
    Xd[kq + 0][rl] = (double)xv0.x; Xd[kq + 1][rl] = (double)xv0.y;
    Xd[kq + 2][rl] = (double)xv0.z; Xd[kq + 3][rl] = (double)xv0.w;
    Xd[kq + 4][rl] = (double)xv1.x; Xd[kq + 5][rl] = (double)xv1.y;
    Xd[kq + 6][rl] = (double)xv1.z; Xd[kq + 7][rl] = (double)xv1.w;
    Wd[kq + 0][rl] = (double)wv0.x; Wd[kq + 1][rl] = (double)wv0.y;
    Wd[kq + 2][rl] = (double)wv0.z; Wd[kq + 3][rl] = (double)wv0.w;
    Wd[kq + 4][rl] = (double)wv1.x; Wd[kq + 5][rl] = (double)wv1.y;
    Wd[kq + 6][rl] = (double)wv1.z; Wd[kq + 7][rl] = (double)wv1.w;
    __syncthreads();
#pragma unroll
    for (int k = 0; k < 32; ++k) {
      const double2 xa = *(const double2*)&Xd[k][ty * 4];
      const double2 xb = *(const double2*)&Xd[k][ty * 4 + 2];
      const double2 wa = *(const double2*)&Wd[k][tx * 4];
      const double2 wb = *(const double2*)&Wd[k][tx * 4 + 2];
      const double xv[4] = {xa.x, xa.y, xb.x, xb.y};
      const double wv[4] = {wa.x, wa.y, wb.x, wb.y};
#pragma unroll
      for (int j = 0; j < 4; ++j)
#pragma unroll
        for (int i = 0; i < 4; ++i) acc[j][i] += xv[j] * wv[i];
    }
  }
  __syncthreads();
#pragma unroll
  for (int j = 0; j < 4; ++j) {
    unsigned int nib = 0u;
#pragma unroll
    for (int i = 0; i < 4; ++i) nib |= (acc[j][i] >= 1.0 ? 1u : 0u) << i;
    atomicOr(&spikes[ty * 4 + j][tx >> 3], nib << ((tx * 4) & 31));
  }
  __syncthreads();
  if (tid < 128) {
    const int r = tid >> 1;
    const int w = tid & 1;
    s1bits[(size_t)(b0 + r) * kFeatWords + (f0 >> 5) + w] = spikes[r][w];
  }
}

__global__ __launch_bounds__(256) void snn_fc2(const unsigned int* __restrict__ s1bits,
                                               const float* __restrict__ W2,
                                               float* __restrict__ out) {
  __shared__ double Wd[32][66];
  __shared__ unsigned int Sb[64];
  const int tid = threadIdx.x;
  const int tx = tid & 15;
  const int ty = tid >> 4;
  const int b0 = blockIdx.y * 64;
  const int o0 = blockIdx.x * 64;
  double acc[4][4];
#pragma unroll
  for (int j = 0; j < 4; ++j)
#pragma unroll
    for (int i = 0; i < 4; ++i) acc[j][i] = 0.0;
  const int rl = tid >> 2;
  const int kq = (tid & 3) * 8;
  int orow = o0 + rl;
  if (orow >= kOut) orow = kOut - 1;
  const float* wrow = W2 + (size_t)orow * kFeat + kq;
  for (int kc = 0; kc < kFeat; kc += 32) {
    const float4 wv0 = *(const float4*)(wrow + kc);
    const float4 wv1 = *(const float4*)(wrow + kc + 4);
    unsigned int sword = 0u;
    if (tid < 64) sword = s1bits[(size_t)(b0 + tid) * kFeatWords + (kc >> 5)];
    __syncthreads();
    Wd[kq + 0][rl] = (double)wv0.x; Wd[kq + 1][rl] = (double)wv0.y;
    Wd[kq + 2][rl] = (double)wv0.z; Wd[kq + 3][rl] = (double)wv0.w;
    Wd[kq + 4][rl] = (double)wv1.x; Wd[kq + 5][rl] = (double)wv1.y;
    Wd[kq + 6][rl] = (double)wv1.z; Wd[kq + 7][rl] = (double)wv1.w;
    if (tid < 64) Sb[tid] = sword;
    __syncthreads();
    const unsigned int rw0 = Sb[ty * 4 + 0];
    const unsigned int rw1 = Sb[ty * 4 + 1];
    const unsigned int rw2 = Sb[ty * 4 + 2];
    const unsigned int rw3 = Sb[ty * 4 + 3];
#pragma unroll
    for (int k = 0; k < 32; ++k) {
      const double2 wa = *(const double2*)&Wd[k][tx * 4];
      const double2 wb = *(const double2*)&Wd[k][tx * 4 + 2];
      const double wv[4] = {wa.x, wa.y, wb.x, wb.y};
      const double sv[4] = {(double)((rw0 >> k) & 1u), (double)((rw1 >> k) & 1u),
                            (double)((rw2 >> k) & 1u), (double)((rw3 >> k) & 1u)};
#pragma unroll
      for (int j = 0; j < 4; ++j)
#pragma unroll
        for (int i = 0; i < 4; ++i) acc[j][i] += sv[j] * wv[i];
    }
  }
#pragma unroll
  for (int j = 0; j < 4; ++j) {
    const int b = b0 + ty * 4 + j;
#pragma unroll
    for (int i = 0; i < 4; ++i) {
      const int o = o0 + tx * 4 + i;
      if (o < kOut) out[(size_t)b * kOut + o] = (acc[j][i] >= 1.0) ? 1.0f : 0.0f;
    }
  }
}

extern "C" void kernel_launch(void* const* d_in, const int* in_sizes, int n_in,
                              void* d_out, int out_size, void* d_ws, size_t ws_size,
                              hipStream_t stream) {
  const float* x = (const float*)d_in[0];
  const float* W1 = (const float*)d_in[1];
  const float* W2 = (const float*)d_in[2];
  float* out = (float*)d_out;

  char* p = (char*)d_ws;
  signed char* w1l = (signed char*)p;                 p += kW1lBytes;
  signed char* w2l = (signed char*)p;                 p += kW2lBytes;
  unsigned* s1b = (unsigned*)p;                       p += kS1Bytes;
  unsigned* xb = (unsigned*)p;                        p += kXbBytes;
  unsigned* list1 = (unsigned*)p;                     p += kList1Bytes;
  unsigned* list2 = (unsigned*)p;                     p += kList2Bytes;
  unsigned* ctrs = (unsigned*)p;                      p += 256;
  const size_t need = (size_t)(p - (char*)d_ws);      // ~82.1 MB

  if (ws_size >= need) {
    // zero BOTH counters: ctrs[0] (FC1) and ctrs[4] (FC2, byte offset 16)
    hipMemsetAsync(ctrs, 0, 32, stream);
    conv_w1_3<<<19208, 256, 0, stream>>>(W1, w1l);
    conv_w2_3<<<3136, 256, 0, stream>>>(W2, w2l);
    pack_x<<<50176, 256, 0, stream>>>(x, xb);
    snn_fc1_i8l3<<<dim3(98, 16), 512, 0, stream>>>(xb, w1l, s1b, ctrs, list1);
    fc1_correct<<<256, 256, 0, stream>>>(x, W1, ctrs, list1, s1b);
    snn_fc2_i8l3<<<dim3(8, 32), 512, 0, stream>>>(s1b, w2l, out, ctrs + 4, list2);
    fc2_correct<<<16, 256, 0, stream>>>(s1b, W2, ctrs + 4, list2, out);
  } else {
    unsigned* s1 = (unsigned*)d_ws;
    snn_fc1<<<dim3(98, 64), 256, 0, stream>>>(x, W1, s1);
    snn_fc2<<<dim3(8, 64), 256, 0, stream>>>(s1, W2, out);
  }
}

// Round 5
// 613.894 us; speedup vs baseline: 8.4622x; 1.2447x over previous
//
#include <hip/hip_runtime.h>

// SNN 2-layer forward: s2 = (( (x@W1.T >=1) @ W2.T) >= 1)
// B=4096, IN=3136, FEAT=6272, OUT=500; x and s1 binary {0,1}.
// Exact 3-limb i8-MFMA GEMM (w = d0*2^-7+d1*2^-14+d2*2^-21+r, |r|<=2^-22,
// i32 accumulation exact, f64 Horner exact) + worst-case-safe sparse fp64
// correction of all dots with |v_hat-1| <= K*2^-22.
//
// Round-5 structure: A-operands (binary) live as packed bits in VGPRs,
// expanded to i8 fragments with (nib*0x204081)&0x01010101 — NO LDS for A.
// LDS carries only B (fragment-contiguous layout w1lF/w2lF, 1KB/slot,
// global_load_lds base+lane*16), double-buffered, ONE barrier per K-iter;
// stage(kt+1) issued after the barrier so its vmcnt drain overlaps compute.
// fc1: tile M=256,N=64, 4 waves, wave m=4 (acc 4x3 v16i=192 regs), 1568 blk.
// fc2: tile M=128,N=64, 4 waves, wave m=2, 256 blk, 98 iters.

namespace {
constexpr int kB = 4096;
constexpr int kIn = 3136;        // 49 chunks of 64
constexpr int kFeat = 6272;      // 98 chunks of 64
constexpr int kFeatWords = 196;  // u32 per s1 row
constexpr int kOut = 500;
constexpr size_t kPlane1 = (size_t)kFeat * kIn;
constexpr size_t kW1F = 3 * kPlane1;                 // 59,006,976 (4802*12288)
constexpr size_t kW2F = (size_t)784 * 12288;         // 9,633,792
constexpr size_t kS1Bytes = (size_t)kB * kFeatWords * 4;  // 3,211,264 (x2: row+T)
constexpr size_t kXb2Bytes = (size_t)49 * kB * 8;    // 1,605,632
constexpr unsigned kCap1 = 2u << 20;
constexpr unsigned kCap2 = 1u << 16;
__device__ constexpr double kTau1 = 7.4769e-4;       // > 3136*2^-22
__device__ constexpr double kTau2 = 1.4955e-3;       // > 6272*2^-22
}  // namespace

typedef int v4i __attribute__((ext_vector_type(4)));
typedef int v16i __attribute__((ext_vector_type(16)));

__device__ __forceinline__ void gload_lds16(const void* g, void* l) {
  __builtin_amdgcn_global_load_lds((__attribute__((address_space(1))) void*)(g),
                                   (__attribute__((address_space(3))) void*)(l),
                                   16, 0, 0);
}

// 16 bits -> 16 i8 (byte i = bit i)
__device__ __forceinline__ v4i expand16(unsigned b) {
  unsigned u0 = (((b      ) & 0xFu) * 0x204081u) & 0x01010101u;
  unsigned u1 = (((b >> 4 ) & 0xFu) * 0x204081u) & 0x01010101u;
  unsigned u2 = (((b >> 8 ) & 0xFu) * 0x204081u) & 0x01010101u;
  unsigned u3 = (((b >> 12) & 0xFu) * 0x204081u) & 0x01010101u;
  return (v4i){(int)u0, (int)u1, (int)u2, (int)u3};
}

// exact 3-digit signed base-128 split; |w - sum| <= 2^-22
__device__ __forceinline__ void split3(float w, signed char* d) {
  float c = rintf(w * 128.f);
  d[0] = (signed char)(int)c;
  float r = fmaf(c, -7.8125e-03f, w);
  c = rintf(r * 16384.f);
  d[1] = (signed char)(int)c;
  r = fmaf(c, -6.103515625e-05f, r);
  c = rintf(r * 2097152.f);
  d[2] = (signed char)(int)c;
}

// ---------------------------------------------------------------------------
// W1 -> fragment-major limbs: slot(fb,kt,j,g) = 1KB of 64 feats x 16 k-bytes.
// addr = ((fb*49+kt)*3 + j)*4096 + g*1024 + f*16 + i ; k = kt*64+g*16+i.
// ---------------------------------------------------------------------------
__global__ __launch_bounds__(256) void conv_w1F(const float* __restrict__ W,
                                                signed char* __restrict__ F) {
  const int bx = blockIdx.x;               // fb*49 + kt, < 4802
  const int fb = bx / 49;
  const int kt = bx % 49;
  const int f = threadIdx.x & 63;
  const int g = threadIdx.x >> 6;
  const float* src = W + (size_t)(fb * 64 + f) * kIn + kt * 64 + g * 16;
  union { signed char c[16]; int4 v; } o[3];
#pragma unroll
  for (int q = 0; q < 4; ++q) {
    const float4 w = *(const float4*)(src + q * 4);
    signed char d[4][3];
    split3(w.x, d[0]); split3(w.y, d[1]); split3(w.z, d[2]); split3(w.w, d[3]);
#pragma unroll
    for (int e = 0; e < 4; ++e)
#pragma unroll
      for (int j = 0; j < 3; ++j) o[j].c[q * 4 + e] = d[e][j];
  }
#pragma unroll
  for (int j = 0; j < 3; ++j)
    *(int4*)(F + ((size_t)bx * 3 + j) * 4096 + g * 1024 + f * 16) = o[j].v;
}

// W2 (padded to 512 rows) -> fragment-major limbs, slots (fb<8, kt<98, j, g)
__global__ __launch_bounds__(256) void conv_w2F(const float* __restrict__ W,
                                                signed char* __restrict__ F) {
  const int bx = blockIdx.x;               // fb*98 + kt, < 784
  const int fb = bx / 98;
  const int kt = bx % 98;
  const int f = threadIdx.x & 63;
  const int g = threadIdx.x >> 6;
  const int feat = fb * 64 + f;
  union { signed char c[16]; int4 v; } o[3];
#pragma unroll
  for (int q = 0; q < 4; ++q) {
    float4 w = {0.f, 0.f, 0.f, 0.f};
    if (feat < kOut)
      w = *(const float4*)(W + (size_t)feat * kFeat + kt * 64 + g * 16 + q * 4);
    signed char d[4][3];
    split3(w.x, d[0]); split3(w.y, d[1]); split3(w.z, d[2]); split3(w.w, d[3]);
#pragma unroll
    for (int e = 0; e < 4; ++e)
#pragma unroll
      for (int j = 0; j < 3; ++j) o[j].c[q * 4 + e] = d[e][j];
  }
#pragma unroll
  for (int j = 0; j < 3; ++j)
    *(int4*)(F + ((size_t)bx * 3 + j) * 4096 + g * 1024 + f * 16) = o[j].v;
}

// x -> transposed packed bits: xb2[kt*4096 + b] = {bits k in [kt*64,+32),[+32,+64)}
__global__ __launch_bounds__(256) void pack_x2(const float* __restrict__ X,
                                               uint2* __restrict__ xb2) {
  const int wid = (blockIdx.x * 256 + threadIdx.x) >> 6;  // < 200,704
  const int lane = threadIdx.x & 63;
  const int b = wid / 49;
  const int g = wid % 49;
  const float v = X[(size_t)b * kIn + g * 64 + lane];
  const unsigned long long bal = __ballot(v != 0.f);
  if (lane == 0) xb2[(size_t)g * kB + b] = make_uint2((unsigned)bal, (unsigned)(bal >> 32));
}

// ---------------------------------------------------------------------------
// FC1: tile M=256,N=64,BK=64; 256 thr = 4 waves (waveM x waveN = 2x2);
// wave: m=4 (128 rows), n=1 (32 cols), acc[4][3] v16i. A bits in VGPR,
// B in LDS dbuf (2 x 12KB), one barrier/iter. Grid (98, 16).
// ---------------------------------------------------------------------------
__global__ __launch_bounds__(256, 2) void fc1_v3(
    const uint2* __restrict__ xb2, const signed char* __restrict__ w1lF,
    unsigned* __restrict__ s1b, unsigned* __restrict__ s1T,
    unsigned* __restrict__ cnt, unsigned* __restrict__ list) {
  __shared__ __align__(16) signed char lds[24576];
  const int tid = threadIdx.x;
  const int lane = tid & 63;
  const int ln31 = lane & 31;
  const int half = lane >> 5;
  const int wv = tid >> 6;
  const int waveM = wv >> 1;
  const int waveN = wv & 1;
  const int bx = blockIdx.x;           // N-block (64 feats)
  const int bM = blockIdx.y * 256;

  // B staging: 12 slots/iter; wave stages s = wv, wv+4, wv+8 (s == j*4+g)
  const signed char* const gbase = w1lF + (size_t)bx * 49 * 12288;
  unsigned sG[3], sL[3];
#pragma unroll
  for (int p = 0; p < 3; ++p) {
    const int s = wv + 4 * p;
    sG[p] = s * 1024u + lane * 16u;
    sL[p] = s * 1024u;
  }
  // A bits: lane covers row bM + waveM*128 + m*32 + ln31
  const uint2* const aptr = xb2 + bM + waveM * 128 + ln31;
  // B fragment read offset inside a buffer: j*4096 + (kk*2+half)*1024 + feat*16
  const unsigned bfeat = (waveN * 32 + ln31) * 16u;

  v16i acc[4][3] = {};
  uint2 abC[4], abN[4];
#pragma unroll
  for (int m = 0; m < 4; ++m) abC[m] = aptr[m * 32];
#pragma unroll
  for (int p = 0; p < 3; ++p) gload_lds16(gbase + sG[p], lds + sL[p]);

  for (int kt = 0; kt < 49; ++kt) {
    __syncthreads();  // drains stage(kt) vmcnt; prev compute done
    const int cb = (kt & 1) * 12288;
    if (kt < 48) {
      const int nb = ((kt + 1) & 1) * 12288;
      const size_t go = (size_t)(kt + 1) * 12288;
#pragma unroll
      for (int p = 0; p < 3; ++p) gload_lds16(gbase + go + sG[p], lds + nb + sL[p]);
#pragma unroll
      for (int m = 0; m < 4; ++m) abN[m] = aptr[(size_t)(kt + 1) * kB + m * 32];
    }
#pragma unroll
    for (int kk = 0; kk < 2; ++kk) {
      const unsigned gsel = (kk * 2 + half) * 1024u;
      const v4i b0 = *(const v4i*)(lds + cb + 0 * 4096 + gsel + bfeat);
      const v4i b1 = *(const v4i*)(lds + cb + 1 * 4096 + gsel + bfeat);
      const v4i b2 = *(const v4i*)(lds + cb + 2 * 4096 + gsel + bfeat);
#pragma unroll
      for (int m = 0; m < 4; ++m) {
        const unsigned word = kk ? abC[m].y : abC[m].x;
        const v4i a = expand16((word >> (half * 16)) & 0xFFFFu);
        acc[m][0] = __builtin_amdgcn_mfma_i32_32x32x32_i8(a, b0, acc[m][0], 0, 0, 0);
        acc[m][1] = __builtin_amdgcn_mfma_i32_32x32x32_i8(a, b1, acc[m][1], 0, 0, 0);
        acc[m][2] = __builtin_amdgcn_mfma_i32_32x32x32_i8(a, b2, acc[m][2], 0, 0, 0);
      }
    }
#pragma unroll
    for (int m = 0; m < 4; ++m) abC[m] = abN[m];
  }

  const double s7 = 0.0078125;
  const int word = bx * 2 + waveN;
  const int fcol = word * 32 + ln31;
#pragma unroll
  for (int m = 0; m < 4; ++m) {
#pragma unroll
    for (int t = 0; t < 16; ++t) {
      double v = (double)acc[m][2][t];
      v = v * s7 + (double)acc[m][1][t];
      v = v * s7 + (double)acc[m][0][t];
      v = v * s7;
      const unsigned long long bal = __ballot(v >= 1.0);
      const int mrow = bM + waveM * 128 + m * 32 + (t & 3) + 8 * (t >> 2);
      if (lane == 0) {
        s1b[(size_t)mrow * kFeatWords + word] = (unsigned)bal;
        s1T[(size_t)word * kB + mrow] = (unsigned)bal;
      }
      if (lane == 32) {
        s1b[(size_t)(mrow + 4) * kFeatWords + word] = (unsigned)(bal >> 32);
        s1T[(size_t)word * kB + mrow + 4] = (unsigned)(bal >> 32);
      }
      if (fabs(v - 1.0) <= kTau1) {
        const unsigned idx = atomicAdd(cnt, 1u);
        if (idx < kCap1) list[idx] = ((unsigned)(mrow + 4 * half) << 13) | (unsigned)fcol;
      }
    }
  }
}

// exact fp64 recompute of flagged FC1 dots; fixes s1b AND s1T
__global__ __launch_bounds__(256) void fc1_correct(
    const float* __restrict__ x, const float* __restrict__ W1,
    const unsigned* __restrict__ cnt, const unsigned* __restrict__ list,
    unsigned* __restrict__ s1b, unsigned* __restrict__ s1T) {
  const unsigned n = min(cnt[0], kCap1);
  const int lane = threadIdx.x & 63;
  const int wid = (blockIdx.x * 256 + threadIdx.x) >> 6;
  const int nw = (gridDim.x * 256) >> 6;
  for (unsigned i = wid; i < n; i += nw) {
    const unsigned u = list[i];
    const int b = (int)(u >> 13);
    const int f = (int)(u & 8191u);
    double s = 0.0;
    for (int k = lane; k < kIn; k += 64)
      s = fma((double)x[(size_t)b * kIn + k], (double)W1[(size_t)f * kIn + k], s);
#pragma unroll
    for (int off = 32; off > 0; off >>= 1) s += __shfl_down(s, off);
    if (lane == 0) {
      const unsigned mask = 1u << (f & 31);
      unsigned* p1 = s1b + (size_t)b * kFeatWords + (f >> 5);
      unsigned* p2 = s1T + (size_t)(f >> 5) * kB + b;
      if (s >= 1.0) { atomicOr(p1, mask); atomicOr(p2, mask); }
      else          { atomicAnd(p1, ~mask); atomicAnd(p2, ~mask); }
    }
  }
}

// ---------------------------------------------------------------------------
// FC2: tile M=128,N=64,BK=64; 256 thr = 4 waves (2x2); wave m=2, acc[2][3].
// A bits from s1T (dword loads), B LDS dbuf, one barrier/iter. Grid (8, 32).
// ---------------------------------------------------------------------------
__global__ __launch_bounds__(256, 2) void fc2_v3(
    const unsigned* __restrict__ s1T, const signed char* __restrict__ w2lF,
    float* __restrict__ out, unsigned* __restrict__ cnt,
    unsigned* __restrict__ list) {
  __shared__ __align__(16) signed char lds[24576];
  const int tid = threadIdx.x;
  const int lane = tid & 63;
  const int ln31 = lane & 31;
  const int half = lane >> 5;
  const int wv = tid >> 6;
  const int waveM = wv >> 1;
  const int waveN = wv & 1;
  const int bx = blockIdx.x;           // N-block (64 outs)
  const int bM = blockIdx.y * 128;

  const signed char* const gbase = w2lF + (size_t)bx * 98 * 12288;
  unsigned sG[3], sL[3];
#pragma unroll
  for (int p = 0; p < 3; ++p) {
    const int s = wv + 4 * p;
    sG[p] = s * 1024u + lane * 16u;
    sL[p] = s * 1024u;
  }
  const unsigned* const aptr = s1T + bM + waveM * 64 + ln31;
  const unsigned bfeat = (waveN * 32 + ln31) * 16u;

  v16i acc[2][3] = {};
  unsigned abC[2][2], abN[2][2];
#pragma unroll
  for (int m = 0; m < 2; ++m)
#pragma unroll
    for (int kk = 0; kk < 2; ++kk) abC[m][kk] = aptr[(size_t)kk * kB + m * 32];
#pragma unroll
  for (int p = 0; p < 3; ++p) gload_lds16(gbase + sG[p], lds + sL[p]);

  for (int kt = 0; kt < 98; ++kt) {
    __syncthreads();
    const int cb = (kt & 1) * 12288;
    if (kt < 97) {
      const int nb = ((kt + 1) & 1) * 12288;
      const size_t go = (size_t)(kt + 1) * 12288;
#pragma unroll
      for (int p = 0; p < 3; ++p) gload_lds16(gbase + go + sG[p], lds + nb + sL[p]);
#pragma unroll
      for (int m = 0; m < 2; ++m)
#pragma unroll
        for (int kk = 0; kk < 2; ++kk)
          abN[m][kk] = aptr[((size_t)(kt + 1) * 2 + kk) * kB + m * 32];
    }
#pragma unroll
    for (int kk = 0; kk < 2; ++kk) {
      const unsigned gsel = (kk * 2 + half) * 1024u;
      const v4i b0 = *(const v4i*)(lds + cb + 0 * 4096 + gsel + bfeat);
      const v4i b1 = *(const v4i*)(lds + cb + 1 * 4096 + gsel + bfeat);
      const v4i b2 = *(const v4i*)(lds + cb + 2 * 4096 + gsel + bfeat);
#pragma unroll
      for (int m = 0; m < 2; ++m) {
        const v4i a = expand16((abC[m][kk] >> (half * 16)) & 0xFFFFu);
        acc[m][0] = __builtin_amdgcn_mfma_i32_32x32x32_i8(a, b0, acc[m][0], 0, 0, 0);
        acc[m][1] = __builtin_amdgcn_mfma_i32_32x32x32_i8(a, b1, acc[m][1], 0, 0, 0);
        acc[m][2] = __builtin_amdgcn_mfma_i32_32x32x32_i8(a, b2, acc[m][2], 0, 0, 0);
      }
    }
#pragma unroll
    for (int m = 0; m < 2; ++m) {
      abC[m][0] = abN[m][0];
      abC[m][1] = abN[m][1];
    }
  }

  const double s7 = 0.0078125;
  const int o = bx * 64 + waveN * 32 + ln31;
#pragma unroll
  for (int m = 0; m < 2; ++m) {
#pragma unroll
    for (int t = 0; t < 16; ++t) {
      double v = (double)acc[m][2][t];
      v = v * s7 + (double)acc[m][1][t];
      v = v * s7 + (double)acc[m][0][t];
      v = v * s7;
      const int b = bM + waveM * 64 + m * 32 + (t & 3) + 8 * (t >> 2) + 4 * half;
      if (o < kOut) {
        out[(size_t)b * kOut + o] = (v >= 1.0) ? 1.0f : 0.0f;
        if (fabs(v - 1.0) <= kTau2) {
          const unsigned idx = atomicAdd(cnt, 1u);
          if (idx < kCap2) list[idx] = ((unsigned)b << 13) | (unsigned)o;
        }
      }
    }
  }
}

// exact fp64 recompute of flagged FC2 dots (reads row-major s1b)
__global__ __launch_bounds__(256) void fc2_correct(
    const unsigned* __restrict__ s1b, const float* __restrict__ W2,
    const unsigned* __restrict__ cnt, const unsigned* __restrict__ list,
    float* __restrict__ out) {
  const unsigned n = min(cnt[0], kCap2);
  const int lane = threadIdx.x & 63;
  const int wid = (blockIdx.x * 256 + threadIdx.x) >> 6;
  const int nw = (gridDim.x * 256) >> 6;
  for (unsigned i = wid; i < n; i += nw) {
    const unsigned u = list[i];
    const int b = (int)(u >> 13);
    const int o = (int)(u & 8191u);
    double s = 0.0;
    for (int k = lane; k < kFeat; k += 64) {
      const unsigned w = s1b[(size_t)b * kFeatWords + (k >> 5)];
      if ((w >> (k & 31)) & 1u) s += (double)W2[(size_t)o * kFeat + k];
    }
#pragma unroll
    for (int off = 32; off > 0; off >>= 1) s += __shfl_down(s, off);
    if (lane == 0) out[(size_t)b * kOut + o] = (s >= 1.0) ? 1.0f : 0.0f;
  }
}

// ---------------------------------------------------------------------------
// fp64 fallback (round-1 validated) — only if ws too small.
// ---------------------------------------------------------------------------
__global__ __launch_bounds__(256) void snn_fc1(const float* __restrict__ x,
                                               const float* __restrict__ W1,
                                               unsigned int* __restrict__ s1bits) {
  __shared__ double Xd[32][66];
  __shared__ double Wd[32][66];
  __shared__ unsigned int spikes[64][2];
  const int tid = threadIdx.x;
  const int tx = tid & 15;
  const int ty = tid >> 4;
  const int b0 = blockIdx.y * 64;
  const int f0 = blockIdx.x * 64;
  if (tid < 128) spikes[tid >> 1][tid & 1] = 0u;
  double acc[4][4];
#pragma unroll
  for (int j = 0; j < 4; ++j)
#pragma unroll
    for (int i = 0; i < 4; ++i) acc[j][i] = 0.0;
  const int rl = tid >> 2;
  const int kq = (tid & 3) * 8;
  const float* xrow = x + (size_t)(b0 + rl) * kIn + kq;
  const float* wrow = W1 + (size_t)(f0 + rl) * kIn + kq;
  for (int kc = 0; kc < kIn; kc += 32) {
    const float4 xv0 = *(const float4*)(xrow + kc);
    const float4 xv1 = *(const float4*)(xrow + kc + 4);
    const float4 wv0 = *(const float4*)(wrow + kc);
    const float4 wv1 = *(const float4*)(wrow + kc + 4);
    __syncthreads();
    Xd[kq + 0][rl] = (double)xv0.x; Xd[kq + 1][rl] = (double)xv0.y;
    Xd[kq + 2][rl] = (double)xv0.z; Xd[kq + 3][rl] = (double)xv0.w;
    Xd[kq + 4][rl] = (double)xv1.x; Xd[kq + 5][rl] = (double)xv1.y;
    Xd[kq + 6][rl] = (double)xv1.z; Xd[kq + 7][rl] = (double)xv1.w;
    Wd[kq + 0][rl] = (double)wv0.x; Wd[kq + 1][rl] = (double)wv0.y;
    Wd[kq + 2][rl] = (double)wv0.z; Wd[kq + 3][rl] = (double)wv0.w;
    Wd[kq + 4][rl] = (double)wv1.x; Wd[kq + 5][rl] = (double)wv1.y;
    Wd[kq + 6][rl] = (double)wv1.z; Wd[kq + 7][rl] = (double)wv1.w;
    __syncthreads();
#pragma unroll
    for (int k = 0; k < 32; ++k) {
      const double2 xa = *(const double2*)&Xd[k][ty * 4];
      const double2 xb = *(const double2*)&Xd[k][ty * 4 + 2];
      const double2 wa = *(const double2*)&Wd[k][tx * 4];
      const double2 wb = *(const double2*)&Wd[k][tx * 4 + 2];
      const double xv[4] = {xa.x, xa.y, xb.x, xb.y};
      const double wv[4] = {wa.x, wa.y, wb.x, wb.y};
#pragma unroll
      for (int j = 0; j < 4; ++j)
#pragma unroll
        for (int i = 0; i < 4; ++i) acc[j][i] += xv[j] * wv[i];
    }
  }
  __syncthreads();
#pragma unroll
  for (int j = 0; j < 4; ++j) {
    unsigned int nib = 0u;
#pragma unroll
    for (int i = 0; i < 4; ++i) nib |= (acc[j][i] >= 1.0 ? 1u : 0u) << i;
    atomicOr(&spikes[ty * 4 + j][tx >> 3], nib << ((tx * 4) & 31));
  }
  __syncthreads();
  if (tid < 128) {
    const int r = tid >> 1;
    const int w = tid & 1;
    s1bits[(size_t)(b0 + r) * kFeatWords + (f0 >> 5) + w] = spikes[r][w];
  }
}

__global__ __launch_bounds__(256) void snn_fc2(const unsigned int* __restrict__ s1bits,
                                               const float* __restrict__ W2,
                                               float* __restrict__ out) {
  __shared__ double Wd[32][66];
  __shared__ unsigned int Sb[64];
  const int tid = threadIdx.x;
  const int tx = tid & 15;
  const int ty = tid >> 4;
  const int b0 = blockIdx.y * 64;
  const int o0 = blockIdx.x * 64;
  double acc[4][4];
#pragma unroll
  for (int j = 0; j < 4; ++j)
#pragma unroll
    for (int i = 0; i < 4; ++i) acc[j][i] = 0.0;
  const int rl = tid >> 2;
  const int kq = (tid & 3) * 8;
  int orow = o0 + rl;
  if (orow >= kOut) orow = kOut - 1;
  const float* wrow = W2 + (size_t)orow * kFeat + kq;
  for (int kc = 0; kc < kFeat; kc += 32) {
    const float4 wv0 = *(const float4*)(wrow + kc);
    const float4 wv1 = *(const float4*)(wrow + kc + 4);
    unsigned int sword = 0u;
    if (tid < 64) sword = s1bits[(size_t)(b0 + tid) * kFeatWords + (kc >> 5)];
    __syncthreads();
    Wd[kq + 0][rl] = (double)wv0.x; Wd[kq + 1][rl] = (double)wv0.y;
    Wd[kq + 2][rl] = (double)wv0.z; Wd[kq + 3][rl] = (double)wv0.w;
    Wd[kq + 4][rl] = (double)wv1.x; Wd[kq + 5][rl] = (double)wv1.y;
    Wd[kq + 6][rl] = (double)wv1.z; Wd[kq + 7][rl] = (double)wv1.w;
    if (tid < 64) Sb[tid] = sword;
    __syncthreads();
    const unsigned int rw0 = Sb[ty * 4 + 0];
    const unsigned int rw1 = Sb[ty * 4 + 1];
    const unsigned int rw2 = Sb[ty * 4 + 2];
    const unsigned int rw3 = Sb[ty * 4 + 3];
#pragma unroll
    for (int k = 0; k < 32; ++k) {
      const double2 wa = *(const double2*)&Wd[k][tx * 4];
      const double2 wb = *(const double2*)&Wd[k][tx * 4 + 2];
      const double wv[4] = {wa.x, wa.y, wb.x, wb.y};
      const double sv[4] = {(double)((rw0 >> k) & 1u), (double)((rw1 >> k) & 1u),
                            (double)((rw2 >> k) & 1u), (double)((rw3 >> k) & 1u)};
#pragma unroll
      for (int j = 0; j < 4; ++j)
#pragma unroll
        for (int i = 0; i < 4; ++i) acc[j][i] += sv[j] * wv[i];
    }
  }
#pragma unroll
  for (int j = 0; j < 4; ++j) {
    const int b = b0 + ty * 4 + j;
#pragma unroll
    for (int i = 0; i < 4; ++i) {
      const int o = o0 + tx * 4 + i;
      if (o < kOut) out[(size_t)b * kOut + o] = (acc[j][i] >= 1.0) ? 1.0f : 0.0f;
    }
  }
}

extern "C" void kernel_launch(void* const* d_in, const int* in_sizes, int n_in,
                              void* d_out, int out_size, void* d_ws, size_t ws_size,
                              hipStream_t stream) {
  const float* x = (const float*)d_in[0];
  const float* W1 = (const float*)d_in[1];
  const float* W2 = (const float*)d_in[2];
  float* out = (float*)d_out;

  char* p = (char*)d_ws;
  signed char* w1lF = (signed char*)p;   p += kW1F;
  signed char* w2lF = (signed char*)p;   p += kW2F;
  unsigned* s1b = (unsigned*)p;          p += kS1Bytes;
  unsigned* s1T = (unsigned*)p;          p += kS1Bytes;
  uint2* xb2 = (uint2*)p;                p += kXb2Bytes;
  unsigned* list1 = (unsigned*)p;        p += (size_t)kCap1 * 4;
  unsigned* list2 = (unsigned*)p;        p += (size_t)kCap2 * 4;
  unsigned* ctrs = (unsigned*)p;         p += 256;
  const size_t need = (size_t)(p - (char*)d_ws);  // ~85 MB

  if (ws_size >= need) {
    hipMemsetAsync(ctrs, 0, 32, stream);  // ctrs[0]=fc1 cnt, ctrs[4]=fc2 cnt
    conv_w1F<<<4802, 256, 0, stream>>>(W1, w1lF);
    conv_w2F<<<784, 256, 0, stream>>>(W2, w2lF);
    pack_x2<<<50176, 256, 0, stream>>>(x, xb2);
    fc1_v3<<<dim3(98, 16), 256, 0, stream>>>(xb2, w1lF, s1b, s1T, ctrs, list1);
    fc1_correct<<<1024, 256, 0, stream>>>(x, W1, ctrs, list1, s1b, s1T);
    fc2_v3<<<dim3(8, 32), 256, 0, stream>>>(s1T, w2lF, out, ctrs + 4, list2);
    fc2_correct<<<64, 256, 0, stream>>>(s1b, W2, ctrs + 4, list2, out);
  } else {
    unsigned* s1 = (unsigned*)d_ws;
    snn_fc1<<<dim3(98, 64), 256, 0, stream>>>(x, W1, s1);
    snn_fc2<<<dim3(8, 64), 256, 0, stream>>>(s1, W2, out);
  }
}